// Round 11
// baseline (373.830 us; speedup 1.0000x reference)
//
#include <hip/hip_runtime.h>
#include <stdint.h>

// ---------------------------------------------------------------------------
// Exact top-k (k=10%) magnitude mask via 16-bit-prefix radix select.
// Six dispatches (round-10 verified structure; + sched_barrier(0) to stop the
// compiler sinking batched loads -- R3/R5 counters showed VGPR_Count=8..16,
// i.e. the 4/8-deep load batches were being serialized to ~1 in flight):
//   init -> hist -> scan16 -> mask_collect -> select_fix -> fill_tail
//
// d_out (33554432 u32 words) scratch layout:
//   [0, 131072)  : two 65536-bin histograms (zeroed by init, filled by hist,
//                  read by scan16, overwritten by matrix-0 mask)
//   [RBASE, end) : candidate (idx,u) pairs, CCAP per matrix (matrix-1 mask
//                  skips this tail; select_fix never writes there;
//                  fill_tail writes it exactly at the end)
// d_ws (64 u32): per matrix m at ws+8*m: [0]=P [1]=rank [3]=T [4]=C;
//   candidate counters ws[32]/ws[48] (own cache lines).
//
// Known harness floor (R9/R10 profiles): 2x fillBufferAligned re-poison
// dispatches ~83us each per iteration -- not controllable from kernel code.
// ---------------------------------------------------------------------------

#define NBINS       65536u
#define CCAP        65536u
#define TOTAL_WORDS 33554432u
#define RWORDS      (2u * CCAP * 2u)                // 262144 words = 1 MiB
#define RBASE       (TOTAL_WORDS - RWORDS)          // 33292288
#define SKIP_WORD   (RBASE - 16777216u)             // 16515072
#define SKIP_F4     (SKIP_WORD / 4u)                // 4128768
#define CNT(m)      (32u + (uint32_t)(m) * 16u)
#define LCAP        256u

typedef float floatx4 __attribute__((ext_vector_type(4)));
__device__ __forceinline__ floatx4 nt_load4(const float4* p) {
  return __builtin_nontemporal_load(reinterpret_cast<const floatx4*>(p));
}

__global__ void init_k(uint32_t* __restrict__ ws, uint32_t* __restrict__ outbuf) {
  uint32_t i = blockIdx.x * blockDim.x + threadIdx.x;
  if (i < 2u * NBINS) outbuf[i] = 0u;
  if (i < 64u) ws[i] = 0u;
}

// PASS 1: full scan, 65536-bin histogram of bits 30..15.
// 128 KiB LDS (2x16-bit packed bins) -> 1 block/CU. 8-deep float4 batching;
// sched_barrier(0) pins all 8 loads BEFORE first use (without it the backend
// sinks each load to its use: ~1 outstanding load/thread, latency-bound).
// Coverage is exact: nvec = 32*S, i0 < S, so base+7S <= nvec-S+i0 < nvec.
__global__ __launch_bounds__(1024, 1) void hist_k(const float* __restrict__ A,
                                                  const float* __restrict__ B,
                                                  uint32_t* __restrict__ outbuf,
                                                  int nvec) {
  const int m = blockIdx.y;
  const float4* __restrict__ src = (const float4*)(m == 0 ? A : B);
  uint32_t* gh = outbuf + (uint32_t)m * NBINS;
  __shared__ uint32_t h[NBINS / 2];
  for (int i = threadIdx.x; i < (int)(NBINS / 2); i += blockDim.x) h[i] = 0u;
  __syncthreads();
  const int i0 = blockIdx.x * blockDim.x + threadIdx.x;
  const int S = gridDim.x * blockDim.x;              // 131072; nvec = 32*S
  for (int base = i0; base < nvec; base += 8 * S) {
    float4 f[8];
#pragma unroll
    for (int q = 0; q < 8; q++) f[q] = src[base + q * S];
    __builtin_amdgcn_sched_barrier(0);               // keep 8 loads in flight
#pragma unroll
    for (int q = 0; q < 8; q++) {
      const float v[4] = {f[q].x, f[q].y, f[q].z, f[q].w};
#pragma unroll
      for (int c = 0; c < 4; c++) {
        uint32_t u = __float_as_uint(v[c]) & 0x7fffffffu;
        uint32_t b = u >> 15;
        atomicAdd(&h[b >> 1], 1u << ((b & 1u) * 16u));
      }
    }
  }
  __syncthreads();
  for (int w = threadIdx.x; w < (int)(NBINS / 2); w += blockDim.x) {
    uint32_t x = h[w];
    uint32_t c0 = x & 0xffffu, c1 = x >> 16;
    if (c0) atomicAdd(&gh[2 * w], c0);
    if (c1) atomicAdd(&gh[2 * w + 1], c1);
  }
}

// Scan the 65536-bin histogram: find bin containing rank j -> P, rank-in-bin.
__global__ __launch_bounds__(1024, 1) void scan16_k(const uint32_t* __restrict__ outbuf,
                                                    uint32_t* __restrict__ ws, uint32_t j) {
  const int m = blockIdx.x;
  const uint32_t* gh = outbuf + (uint32_t)m * NBINS;
  uint32_t* W = ws + m * 8;
  __shared__ uint32_t csum[1024];
  __shared__ uint32_t ps[1024];
  __shared__ uint32_t sChunk, sRank;
  __shared__ uint32_t bins[64];
  const int t = threadIdx.x;
  const int w = t >> 6, l = t & 63;
  for (int k = 0; k < 64; k++) {
    uint32_t v = gh[(w << 12) + (k << 6) + l];       // coalesced 256B line
#pragma unroll
    for (int off = 32; off; off >>= 1) v += __shfl_xor(v, off, 64);
    if (l == 0) csum[(w << 6) + k] = v;
  }
  __syncthreads();
  ps[t] = csum[t];
  __syncthreads();
  for (int off = 1; off < 1024; off <<= 1) {
    uint32_t v = (t >= off) ? ps[t - off] : 0u;
    __syncthreads();
    ps[t] += v;
    __syncthreads();
  }
  uint32_t base = (t == 0) ? 0u : ps[t - 1];
  if (j >= base && j < base + csum[t]) { sChunk = (uint32_t)t; sRank = j - base; }
  __syncthreads();
  const uint32_t chunk = sChunk, rk = sRank;
  if (t < 64) bins[t] = gh[chunk * 64u + (uint32_t)t];
  __syncthreads();
  if (t < 64) {
    uint32_t lt = 0u;
    for (int k2 = 0; k2 < t; k2++) lt += bins[k2];
    if (rk >= lt && rk < lt + bins[t]) { W[0] = chunk * 64u + (uint32_t)t; W[1] = rk - lt; }
  }
}

// PASS 2 (fused with final mask): provisional mask by 16-bit prefix compare;
// candidates staged in LDS, ONE global atomicAdd per block. 1024 threads x
// 512x2 blocks x 8-deep = exact coverage (no guards). sched_barrier(0) keeps
// the 8 NT loads in flight (128 B/thread) instead of compiler-sunk 1-deep.
__global__ __launch_bounds__(1024) void mask_collect_k(
    const float* __restrict__ A, const float* __restrict__ B,
    float* __restrict__ out, uint32_t* __restrict__ ws,
    uint32_t* __restrict__ outbuf, int nvec, int n) {
  const int m = blockIdx.y;
  const float4* __restrict__ src = (const float4*)(m == 0 ? A : B);
  float4* __restrict__ dst = (float4*)(out + (size_t)m * (size_t)n);
  const uint32_t P = ws[m * 8];
  uint32_t* cand = outbuf + RBASE + (uint32_t)m * (CCAP * 2u);
  __shared__ uint32_t lbuf[2u * LCAP];
  __shared__ uint32_t ln, lbase;
  if (threadIdx.x == 0) ln = 0u;
  __syncthreads();
  const int i0 = blockIdx.x * blockDim.x + threadIdx.x;
  const int S = gridDim.x * blockDim.x;              // 524288; nvec == 8*S exactly
  floatx4 f[8];
#pragma unroll
  for (int q = 0; q < 8; q++) f[q] = nt_load4(&src[i0 + q * S]);
  __builtin_amdgcn_sched_barrier(0);                 // keep 8 loads in flight
#pragma unroll
  for (int q = 0; q < 8; q++) {
    const int i = i0 + q * S;
    const float v[4] = {f[q].x, f[q].y, f[q].z, f[q].w};
    float r[4];
#pragma unroll
    for (int c = 0; c < 4; c++) {
      uint32_t u = __float_as_uint(v[c]) & 0x7fffffffu;
      uint32_t p = u >> 15;
      r[c] = (p > P) ? 1.0f : 0.0f;          // p==P resolved by select_fix_k
      if (p == P) {
        uint32_t s = atomicAdd(&ln, 1u);     // LDS atomic: cheap, rare (~0.2%)
        if (s < LCAP) { lbuf[2u * s] = (uint32_t)i * 4u + (uint32_t)c; lbuf[2u * s + 1u] = u; }
      }
    }
    if (!(m == 1 && i >= (int)SKIP_F4))
      dst[i] = make_float4(r[0], r[1], r[2], r[3]);
  }
  __syncthreads();
  uint32_t c = ln; if (c > LCAP) c = LCAP;
  if (threadIdx.x == 0 && c) lbase = atomicAdd(&ws[CNT(m)], c);   // ONE global atomic/block
  __syncthreads();
  for (uint32_t t = threadIdx.x; t < c; t += blockDim.x) {
    uint32_t g = lbase + t;
    if (g < CCAP) { cand[2u * g] = lbuf[2u * t]; cand[2u * g + 1u] = lbuf[2u * t + 1u]; }
  }
}

// Exact select among candidates: 15 remaining bits -> 32768-bin LDS histogram
// gives the EXACT threshold T; selected bin IS the tie set. Resolve tie cutoff
// C, scatter-fix candidate entries. Never writes words >= RBASE.
__global__ __launch_bounds__(1024, 1) void select_fix_k(uint32_t* __restrict__ ws,
                                                        uint32_t* __restrict__ outbuf,
                                                        float* __restrict__ out, int n) {
  const int m = blockIdx.x;
  uint32_t* W = ws + m * 8;
  const uint32_t* cand = outbuf + RBASE + (uint32_t)m * (CCAP * 2u);
  __shared__ uint32_t h[32768];
  __shared__ uint32_t ps[1024];
  __shared__ uint32_t sT, sTarget, sC;
  __shared__ uint32_t tie_idx[1024];
  __shared__ uint32_t tie_n;
  const int t = threadIdx.x;
  uint32_t nc = ws[CNT(m)]; if (nc > CCAP) nc = CCAP;
  const uint32_t r = W[1];
  const uint32_t P = W[0];
  if (t == 0) { tie_n = 0u; sT = P << 15; sTarget = 0u; sC = 0u; }
  for (int i = t; i < 32768; i += 1024) h[i] = 0u;
  __syncthreads();
  for (uint32_t e = t; e < nc; e += 1024u)
    atomicAdd(&h[cand[2u * e + 1u] & 32767u], 1u);
  __syncthreads();
  uint32_t s = 0u;
  for (int k = 0; k < 32; k++) s += h[t * 32 + k];
  ps[t] = s;
  __syncthreads();
  for (int off = 1; off < 1024; off <<= 1) {
    uint32_t v = (t >= off) ? ps[t - off] : 0u;
    __syncthreads();
    ps[t] += v;
    __syncthreads();
  }
  uint32_t base = (t == 0) ? 0u : ps[t - 1];
  for (int k = 0; k < 32; k++) {
    uint32_t b = (uint32_t)t * 32u + (uint32_t)k;
    uint32_t c = h[b];
    if (r >= base && r < base + c) { sT = (P << 15) | b; sTarget = r - base; }
    base += c;
  }
  __syncthreads();
  const uint32_t T = sT, target = sTarget;
  for (uint32_t e = t; e < nc; e += 1024u) {
    if (cand[2u * e + 1u] == T) {
      uint32_t slot = atomicAdd(&tie_n, 1u);
      if (slot < 1024u) tie_idx[slot] = cand[2u * e];
    }
  }
  __syncthreads();
  uint32_t E2 = tie_n; if (E2 > 1024u) E2 = 1024u;
  for (uint32_t c2 = t; c2 < E2; c2 += 1024u) {
    uint32_t xi = tie_idx[c2];
    uint32_t lt = 0u;
    for (uint32_t k2 = 0; k2 < E2; k2++) lt += (tie_idx[k2] < xi) ? 1u : 0u;
    if (lt == target) sC = xi;               // target-th smallest tie index
  }
  __syncthreads();
  if (t == 0) { W[3] = T; W[4] = sC; }
  const uint32_t C = sC;
  float* dstf = out + (size_t)m * (size_t)n;
  for (uint32_t e = t; e < nc; e += 1024u) {
    uint32_t idx = cand[2u * e];
    if (m == 1 && idx >= SKIP_WORD) continue;   // covered by fill_tail_k
    uint32_t u = cand[2u * e + 1u];
    dstf[idx] = (u > T || (u == T && idx >= C)) ? 1.0f : 0.0f;
  }
}

// Fill the tail region of matrix-1's output with the exact rule.
__global__ void fill_tail_k(const float* __restrict__ B, float* __restrict__ out,
                            const uint32_t* __restrict__ ws, int n) {
  const uint32_t* W = ws + 8;
  const uint32_t T = W[3], C = W[4];
  const float4* __restrict__ src = (const float4*)B;
  float4* __restrict__ dst = (float4*)(out + (size_t)n);
  uint32_t i = SKIP_F4 + blockIdx.x * blockDim.x + threadIdx.x;
  if (i < (uint32_t)(n / 4)) {
    float4 f = src[i];
    const float v[4] = {f.x, f.y, f.z, f.w};
    float r[4];
#pragma unroll
    for (int c = 0; c < 4; c++) {
      uint32_t u = __float_as_uint(v[c]) & 0x7fffffffu;
      uint32_t idx = i * 4u + (uint32_t)c;
      r[c] = (u > T || (u == T && idx >= C)) ? 1.0f : 0.0f;
    }
    dst[i] = make_float4(r[0], r[1], r[2], r[3]);
  }
}

extern "C" void kernel_launch(void* const* d_in, const int* in_sizes, int n_in,
                              void* d_out, int out_size, void* d_ws, size_t ws_size,
                              hipStream_t stream) {
  const float* A = (const float*)d_in[0];
  const float* B = (const float*)d_in[1];
  float* out = (float*)d_out;
  uint32_t* ws = (uint32_t*)d_ws;
  uint32_t* outbuf = (uint32_t*)d_out;
  const int n = in_sizes[0];                               // 16777216 per matrix
  const int nvec = n / 4;
  const uint32_t j = (uint32_t)((1.0 - 0.1) * (double)n);  // == Python int((1-k)*n)

  init_k<<<(2u * NBINS + 255) / 256, 256, 0, stream>>>(ws, outbuf);
  hist_k<<<dim3(128, 2), 1024, 0, stream>>>(A, B, outbuf, nvec);
  scan16_k<<<2, 1024, 0, stream>>>(outbuf, ws, j);
  mask_collect_k<<<dim3(512, 2), 1024, 0, stream>>>(A, B, out, ws, outbuf, nvec, n);
  select_fix_k<<<2, 1024, 0, stream>>>(ws, outbuf, out, n);
  fill_tail_k<<<(n / 4 - SKIP_F4 + 255) / 256, 256, 0, stream>>>(B, out, ws, n);
}